// Round 11
// baseline (39.128 us; speedup 1.0000x reference)
//
#include <hip/hip_runtime.h>
#include <hip/hip_bf16.h>
#include <stdint.h>

// costh[B,CK] = (x/||x||_row) @ (W/||W||_col),  x:[B,D] f32, W:[D,CK] f32
// B=512, D=512, CK=5994*3=17982. Output f32.
// Kernel 1 (prep): W -> Wt bf16 granule tiles (register transpose, coalesced
//   both sides, cvt_pk) + per-column partial sumsq; x -> An normalized tiles.
// Kernel 2 (gemm): 128x128 tile, ZERO-LDS register-direct fragment loads
//   (granule layout == fragment layout, 16B/lane coalesced L2 reads),
//   NO barriers in the K-loop — waves fully independent. LDS only for the
//   full-line epilogue + winv.

#define D_DIM 512
#define BM 128
#define BN 128
#define KITERS 16                  // K-steps of 32
#define TILE_BYTES (64 * BM * 16)  // 131072 B per 128-row tile

typedef __bf16 bf16x8 __attribute__((ext_vector_type(8)));
typedef __bf16 bf16x2 __attribute__((ext_vector_type(2)));
typedef float f32x4 __attribute__((ext_vector_type(4)));

__device__ __forceinline__ unsigned pk(float a, float b) {
  bf16x2 t; t[0] = (__bf16)a; t[1] = (__bf16)b;   // v_cvt_pk_bf16_f32 (RNE)
  return __builtin_bit_cast(unsigned, t);
}

// ---------------- kernel 1: prep (wtrans units + xnorm units) ----------------
__global__ void prep_kernel(const float* __restrict__ x, const float* __restrict__ W,
                            unsigned short* __restrict__ An, unsigned short* __restrict__ Wt,
                            float* __restrict__ partial, int CK, int NT128, int nWtBlocks) {
  const int b = blockIdx.x;
  const int t = threadIdx.x;
  if (b < nWtBlocks) {
    __shared__ float red[8 * 128];
    const int ntile = b >> 3, gb = b & 7;
    const int cq = t & 31, dr = t >> 5;
    const int n0 = ntile * BN;
    const int nb = n0 + cq * 4;
    const int g = gb * 8 + dr;               // granule (k/8)
    float ss0 = 0.f, ss1 = 0.f, ss2 = 0.f, ss3 = 0.f;
    unsigned int gr[4][4];                   // [col][pair] packed bf16x2
    if (n0 + BN <= CK) {
#pragma unroll
      for (int i = 0; i < 8; i += 2) {
        float4 v0 = *(const float4*)(W + (size_t)(g * 8 + i) * CK + nb);
        float4 v1 = *(const float4*)(W + (size_t)(g * 8 + i + 1) * CK + nb);
        ss0 += v0.x * v0.x + v1.x * v1.x; ss1 += v0.y * v0.y + v1.y * v1.y;
        ss2 += v0.z * v0.z + v1.z * v1.z; ss3 += v0.w * v0.w + v1.w * v1.w;
        gr[0][i >> 1] = pk(v0.x, v1.x);
        gr[1][i >> 1] = pk(v0.y, v1.y);
        gr[2][i >> 1] = pk(v0.z, v1.z);
        gr[3][i >> 1] = pk(v0.w, v1.w);
      }
    } else {
      float acc_ss[4] = {0.f, 0.f, 0.f, 0.f};
#pragma unroll
      for (int i = 0; i < 8; i += 2) {
#pragma unroll
        for (int e = 0; e < 4; ++e) {
          const int n = nb + e;
          const float f0 = (n < CK) ? W[(size_t)(g * 8 + i) * CK + n] : 0.f;
          const float f1 = (n < CK) ? W[(size_t)(g * 8 + i + 1) * CK + n] : 0.f;
          acc_ss[e] += f0 * f0 + f1 * f1;
          gr[e][i >> 1] = pk(f0, f1);
        }
      }
      ss0 = acc_ss[0]; ss1 = acc_ss[1]; ss2 = acc_ss[2]; ss3 = acc_ss[3];
    }
    unsigned short* dst = Wt + (size_t)ntile * (TILE_BYTES / 2) + (size_t)g * (BM * 8) + (size_t)cq * 32;
#pragma unroll
    for (int e = 0; e < 4; ++e) {
      uint4 o; o.x = gr[e][0]; o.y = gr[e][1]; o.z = gr[e][2]; o.w = gr[e][3];
      *(uint4*)(dst + e * 8) = o;
    }
    *(float4*)(&red[dr * 128 + cq * 4]) = make_float4(ss0, ss1, ss2, ss3);
    __syncthreads();
    if (t < 128) {
      float s = 0.f;
#pragma unroll
      for (int k = 0; k < 8; ++k) s += red[k * 128 + t];
      partial[(size_t)gb * NT128 + n0 + t] = s;
    }
  } else {
    // xnorm: 4 rows per block, one wave per row
    const int w = t >> 6, lane = t & 63;
    const int m = (b - nWtBlocks) * 4 + w;
    const float* xr = x + (size_t)m * D_DIM + lane * 8;
    float4 a = *(const float4*)(xr);
    float4 c = *(const float4*)(xr + 4);
    float s = a.x * a.x + a.y * a.y + a.z * a.z + a.w * a.w +
              c.x * c.x + c.y * c.y + c.z * c.z + c.w * c.w;
#pragma unroll
    for (int off = 32; off; off >>= 1) s += __shfl_xor(s, off, 64);
    const float inv = 1.f / fmaxf(sqrtf(s), 1e-8f);
    ushort4 o0, o1;
    const unsigned p0 = pk(a.x * inv, a.y * inv), p1 = pk(a.z * inv, a.w * inv);
    const unsigned p2 = pk(c.x * inv, c.y * inv), p3 = pk(c.z * inv, c.w * inv);
    o0.x = (unsigned short)(p0 & 0xffff); o0.y = (unsigned short)(p0 >> 16);
    o0.z = (unsigned short)(p1 & 0xffff); o0.w = (unsigned short)(p1 >> 16);
    o1.x = (unsigned short)(p2 & 0xffff); o1.y = (unsigned short)(p2 >> 16);
    o1.z = (unsigned short)(p3 & 0xffff); o1.w = (unsigned short)(p3 >> 16);
    const int mtile = m >> 7, r = m & 127;
    unsigned short* dst = An + (size_t)mtile * (TILE_BYTES / 2) + (size_t)lane * (BM * 8) + r * 8;
    *(ushort4*)dst = o0;
    *(ushort4*)(dst + 4) = o1;
  }
}

// ---------------- kernel 2: GEMM, zero-LDS register-direct, no barriers ----------------
__global__ __launch_bounds__(256, 3) void gemm_kernel(const unsigned short* __restrict__ An,
                                                      const unsigned short* __restrict__ Wt,
                                                      const float* __restrict__ partial,
                                                      float* __restrict__ out, int CK, int NT128) {
  __shared__ __attribute__((aligned(16))) unsigned char lds[36864];  // winv + epilogue only
  // bijective XCD swizzle (m204); 4 consecutive wg (one ntile) share an XCD
  const int total = gridDim.x;
  const int q = total >> 3, rr = total & 7;
  const int lin = blockIdx.x;
  const int xcd = lin & 7, idx = lin >> 3;
  const int wg = ((xcd < rr) ? xcd * (q + 1) : rr * (q + 1) + (xcd - rr) * q) + idx;
  const int ntile = wg >> 2, mtile = wg & 3;

  const int t = threadIdx.x;
  const int lane = t & 63, w = t >> 6;
  const int wm = w >> 1, wn = w & 1;          // wave -> 64x64 quadrant
  const int lrow = lane & 15;
  const int kg = lane >> 4;                   // k-granule slot 0..3

  // fragment base pointers: granule layout IS fragment layout.
  // frag(kt, i) = 16B at base + kt*8192 + i*256
  const unsigned char* pa = (const unsigned char*)An + (size_t)mtile * TILE_BYTES
                            + kg * 2048 + (wm * 64 + lrow) * 16;
  const unsigned char* pb = (const unsigned char*)Wt + (size_t)ntile * TILE_BYTES
                            + kg * 2048 + (wn * 64 + lrow) * 16;
  const int n0 = ntile * BN;
  const bool full = (n0 + BN <= CK);

  f32x4 acc[4][4] = {};
  bf16x8 fa[2][4], fb[2][4];

#define LOADSET(s, P_A, P_B)                                                  \
  {                                                                           \
    _Pragma("unroll")                                                         \
    for (int i = 0; i < 4; ++i) fa[s][i] = *(const bf16x8*)((P_A) + i * 256); \
    _Pragma("unroll")                                                         \
    for (int i = 0; i < 4; ++i) fb[s][i] = *(const bf16x8*)((P_B) + i * 256); \
  }

  LOADSET(0, pa, pb);

#pragma unroll
  for (int kt = 0; kt < KITERS; ++kt) {
    const int s = kt & 1;
    if (kt + 1 < KITERS) {
      const unsigned char* na = pa + (size_t)(kt + 1) * 8192;
      const unsigned char* nb = pb + (size_t)(kt + 1) * 8192;
      LOADSET(s ^ 1, na, nb);                 // next set in flight during MFMAs
    }
#pragma unroll
    for (int i = 0; i < 4; ++i)
#pragma unroll
      for (int j = 0; j < 4; ++j)
        acc[i][j] = __builtin_amdgcn_mfma_f32_16x16x32_bf16(fa[s][i], fb[s][j], acc[i][j], 0, 0, 0);
  }
#undef LOADSET

  // ---- winv (first LDS use in kernel) ----
  float* winv = (float*)lds;             // 128 f32 at base
  if (t < 128) {
    float s = 0.f;
#pragma unroll
    for (int k = 0; k < 8; ++k) s += partial[(size_t)k * NT128 + n0 + t];
    winv[t] = 1.f / fmaxf(sqrtf(s), 1e-8f);
  }
  __syncthreads();
  float wv[4];
#pragma unroll
  for (int j = 0; j < 4; ++j) wv[j] = winv[wn * 64 + j * 16 + lrow];

  // ---- epilogue: full-line writes via wave-private padded LDS ----
  if (full) {
    float* stg = (float*)(lds + 1024) + w * 2176;   // 32*68 floats per wave
    const int l15 = lane & 15, l4 = lane >> 4;
#pragma unroll
    for (int half = 0; half < 2; ++half) {
#pragma unroll
      for (int di = 0; di < 2; ++di)
#pragma unroll
        for (int j = 0; j < 4; ++j)
#pragma unroll
          for (int jj = 0; jj < 4; ++jj)
            stg[(di * 16 + kg * 4 + jj) * 68 + j * 16 + lrow] = acc[half * 2 + di][j][jj] * wv[j];
      // wave-private region: per-wave lgkm ordering suffices, no barrier
#pragma unroll
      for (int s = 0; s < 8; ++s) {
        const int rl = s * 4 + l4;
        float4 v = *(float4*)&stg[rl * 68 + l15 * 4];
        const int row = mtile * BM + wm * 64 + half * 32 + rl;
        *(float4*)&out[(size_t)row * CK + n0 + wn * 64 + l15 * 4] = v;
      }
    }
  } else {
    // tail tile only: scalar stores with bounds check
#pragma unroll
    for (int j = 0; j < 4; ++j) {
      const int col = n0 + wn * 64 + j * 16 + lrow;
      if (col < CK) {
#pragma unroll
        for (int i = 0; i < 4; ++i)
#pragma unroll
          for (int jj = 0; jj < 4; ++jj) {
            const int row = mtile * BM + wm * 64 + i * 16 + kg * 4 + jj;
            out[(size_t)row * CK + col] = acc[i][j][jj] * wv[j];
          }
      }
    }
  }
}

extern "C" void kernel_launch(void* const* d_in, const int* in_sizes, int n_in,
                              void* d_out, int out_size, void* d_ws, size_t ws_size,
                              hipStream_t stream) {
  const float* x = (const float*)d_in[0];
  const float* W = (const float*)d_in[1];
  float* out = (float*)d_out;
  const int Bn = in_sizes[0] / D_DIM;     // 512
  const int CK = in_sizes[1] / D_DIM;     // 17982
  const int ntiles = (CK + BN - 1) / BN;  // 141
  const int mtiles = Bn / BM;             // 4
  const int NT128 = ntiles * BN;          // 18048

  unsigned char* ws = (unsigned char*)d_ws;
  float* partial = (float*)ws;                                  // 8*NT128*4 = 577536 B
  unsigned short* An = (unsigned short*)(ws + 8 * (size_t)NT128 * 4);
  unsigned short* Wt = (unsigned short*)(ws + 8 * (size_t)NT128 * 4 + (size_t)mtiles * TILE_BYTES);

  const int nWtBlocks = ntiles * 8;
  const int nXBlocks = Bn / 4;            // 128
  hipLaunchKernelGGL(prep_kernel, dim3(nWtBlocks + nXBlocks), dim3(256), 0, stream,
                     x, W, An, Wt, partial, CK, NT128, nWtBlocks);
  hipLaunchKernelGGL(gemm_kernel, dim3(ntiles * mtiles), dim3(256), 0, stream,
                     An, Wt, partial, out, CK, NT128);
}